// Round 8
// baseline (38.674 us; speedup 1.0000x reference)
//
#include <hip/hip_runtime.h>
#include <cmath>

#define NK       10000
#define GROUP    2000
#define SEQ_L    256
#define FEAT_DIM 20000
#define NBATCH   16

typedef _Float16 half8 __attribute__((ext_vector_type(8)));
typedef float    f32x4 __attribute__((ext_vector_type(4)));

// ---------------------------------------------------------------------------
// Kernel 1: fused im2col-build + MFMA GEMM + max/PPV epilogue.
//   Block = 256 thr (4 waves) owns 256 kernel rows x 256 positions of one
//   (dilation group, batch). B (im2col hi/lo fp16 split, bias folded in at
//   k'=27 with B[27][t]=1) is built ONCE per block into LDS; fragments are
//   conflict-free ds_read_b128. 3-term split (hh+lh+hl) = ~f32 accuracy.
// grid = (8 Mtiles, 5 groups, 16 batches).
// ---------------------------------------------------------------------------
__launch_bounds__(256)
__global__ void rocket_gemm(const float* __restrict__ x_enc,  // (16,256,3)
                            const float* __restrict__ Wk,     // (10000,3,9)
                            const float* __restrict__ bias,   // (10000,)
                            float* __restrict__ feat)         // (16,20000)
{
    __shared__ __align__(16) float    xp[3 * 384];     // [c][t+64] zero-padded
    __shared__ __align__(16) _Float16 Bh[1024 * 8];    // [kb*256+t][j]
    __shared__ __align__(16) _Float16 Bl[1024 * 8];

    const int mt  = blockIdx.x;        // M tile 0..7 (256 rows)
    const int gi  = blockIdx.y;        // dilation group 0..4
    const int b   = blockIdx.z;
    const int d   = 1 << gi;
    const int tid = threadIdx.x;
    const int l   = tid & 63;
    const int wv  = tid >> 6;          // wave 0..3 -> 64-row slice
    const int kb  = l >> 4;            // k-block 0..3
    const int lr  = l & 15;

    // ---- stage padded x ----
    for (int i = tid; i < 3 * 384; i += 256) xp[i] = 0.f;
    __syncthreads();
    for (int e = tid; e < SEQ_L * 3; e += 256) {
        const int t = e / 3;
        const int c = e - t * 3;
        xp[c * 384 + 64 + t] = x_enc[(b * SEQ_L + t) * 3 + c];
    }

    // ---- A fragments (weights, bias folded at k=27), global -> registers ----
    half8 ahi[4], alo[4];
#pragma unroll
    for (int tt = 0; tt < 4; ++tt) {
        const int nl = mt * 256 + wv * 64 + tt * 16 + lr;
        const int n  = gi * GROUP + (nl < GROUP ? nl : GROUP - 1);
#pragma unroll
        for (int j = 0; j < 8; ++j) {
            const int k = kb * 8 + j;
            float w;
            if (k < 27)       w = Wk[n * 27 + k];
            else if (k == 27) w = bias[n];
            else              w = 0.f;
            const _Float16 h = (_Float16)w;
            ahi[tt][j] = h;
            alo[tt][j] = (_Float16)(w - (float)h);
        }
    }

    __syncthreads();   // xp ready

    // ---- build B hi/lo in LDS (once per block) ----
#pragma unroll
    for (int q = 0; q < 4; ++q) {
        const int idx = q * 256 + tid;     // kb*256 + t
        const int kbb = idx >> 8;
        const int t   = idx & 255;
        half8 hv, lv;
#pragma unroll
        for (int kk = 0; kk < 8; ++kk) {
            const int k2 = kbb * 8 + kk;
            float v = 0.f;
            if (k2 < 27) {
                const int c  = (k2 >= 18) ? 2 : (k2 >= 9 ? 1 : 0);
                const int k9 = k2 - c * 9;
                v = xp[c * 384 + 64 + t + (k9 - 4) * d];
            } else if (k2 == 27) {
                v = 1.0f;                   // bias row
            }
            const _Float16 h = (_Float16)v;
            hv[kk] = h;
            lv[kk] = (_Float16)(v - (float)h);
        }
        *(half8*)&Bh[idx * 8] = hv;
        *(half8*)&Bl[idx * 8] = lv;
    }
    __syncthreads();

    // ---- MFMA main loop: 16 N-chunks of 16 cols ----
    float mx[4][4];
    int   cnt[4][4];
#pragma unroll
    for (int tt = 0; tt < 4; ++tt)
#pragma unroll
        for (int r = 0; r < 4; ++r) { mx[tt][r] = -INFINITY; cnt[tt][r] = 0; }

#pragma unroll
    for (int ch = 0; ch < 16; ++ch) {
        const int t = ch * 16 + lr;
        const half8 bh = *(const half8*)&Bh[(kb * 256 + t) * 8];
        const half8 bl = *(const half8*)&Bl[(kb * 256 + t) * 8];
#pragma unroll
        for (int tt = 0; tt < 4; ++tt) {
            f32x4 acc = {0.f, 0.f, 0.f, 0.f};
            acc = __builtin_amdgcn_mfma_f32_16x16x32_f16(ahi[tt], bh, acc, 0, 0, 0);
            acc = __builtin_amdgcn_mfma_f32_16x16x32_f16(alo[tt], bh, acc, 0, 0, 0);
            acc = __builtin_amdgcn_mfma_f32_16x16x32_f16(ahi[tt], bl, acc, 0, 0, 0);
#pragma unroll
            for (int r = 0; r < 4; ++r) {
                const float y = acc[r];              // bias already included
                mx[tt][r]   = fmaxf(mx[tt][r], y);
                cnt[tt][r] += (y > 0.f) ? 1 : 0;
            }
        }
    }

    // ---- reduce over the 16 columns (lanes with same row group) ----
#pragma unroll
    for (int tt = 0; tt < 4; ++tt)
#pragma unroll
        for (int r = 0; r < 4; ++r) {
#pragma unroll
            for (int m = 1; m < 16; m <<= 1) {
                mx[tt][r]   = fmaxf(mx[tt][r], __shfl_xor(mx[tt][r], m));
                cnt[tt][r] += __shfl_xor(cnt[tt][r], m);
            }
        }

    if (lr == 0) {
        float* fb = feat + b * FEAT_DIM + gi * 4000;
#pragma unroll
        for (int tt = 0; tt < 4; ++tt)
#pragma unroll
            for (int r = 0; r < 4; ++r) {
                const int nl = mt * 256 + wv * 64 + tt * 16 + kb * 4 + r;
                if (nl < GROUP) {
                    fb[nl]        = mx[tt][r];
                    fb[2000 + nl] = (float)cnt[tt][r] * (1.0f / 256.0f);
                }
            }
    }
}

// ---------------------------------------------------------------------------
// Kernel 2: fused BN-stats + GEMV partial. 160 slices of 125 features.
//   linW slice staged in LDS (coalesced); g,h computed in LDS; 16x16
//   (batch x f-lane) phase-2 with shfl reduce.
// ---------------------------------------------------------------------------
__launch_bounds__(256)
__global__ void bn_gemv(const float* __restrict__ feat,
                        const float* __restrict__ gamma,
                        const float* __restrict__ beta,
                        const float* __restrict__ linW,   // (20000,10)
                        float* __restrict__ partial)      // (160,16,10)
{
    __shared__ float gs[125], hs[125];
    __shared__ float lw[125 * 10];
    const int sl  = blockIdx.x;
    const int f0  = sl * 125;
    const int tid = threadIdx.x;

    for (int i = tid; i < 1250; i += 256) lw[i] = linW[f0 * 10 + i];

    if (tid < 125) {
        const int f = f0 + tid;
        float s = 0.f, ss = 0.f;
#pragma unroll
        for (int b = 0; b < NBATCH; ++b) {
            const float v = feat[b * FEAT_DIM + f];
            s += v; ss += v * v;
        }
        const float mu  = s * (1.f / NBATCH);
        const float var = ss * (1.f / NBATCH) - mu * mu;
        const float gg  = gamma[f] * rsqrtf(var + 1e-5f);
        gs[tid] = gg;
        hs[tid] = beta[f] - mu * gg;
    }
    __syncthreads();

    const int bb = tid >> 4;        // batch 0..15
    const int ft = tid & 15;
    float acc[10];
#pragma unroll
    for (int c = 0; c < 10; ++c) acc[c] = 0.f;

    for (int i = ft; i < 125; i += 16) {
        const float tv = fmaf(feat[bb * FEAT_DIM + f0 + i], gs[i], hs[i]);
#pragma unroll
        for (int c = 0; c < 10; ++c) acc[c] = fmaf(tv, lw[i * 10 + c], acc[c]);
    }
#pragma unroll
    for (int c = 0; c < 10; ++c)
#pragma unroll
        for (int m = 1; m < 16; m <<= 1) acc[c] += __shfl_xor(acc[c], m);

    if (ft == 0) {
#pragma unroll
        for (int c = 0; c < 10; ++c)
            partial[(sl * NBATCH + bb) * 10 + c] = acc[c];
    }
}

// ---------------------------------------------------------------------------
// Kernel 3: final reduce over 160 slices + bias. 1 block, 640 threads.
// ---------------------------------------------------------------------------
__launch_bounds__(640)
__global__ void gemv_final(const float* __restrict__ partial,  // (160,160)
                           const float* __restrict__ linB,
                           float* __restrict__ out)            // (16,10)
{
    __shared__ float red[4][160];
    const int tid = threadIdx.x;
    const int q   = tid / 160;      // 0..3
    const int o   = tid - q * 160;  // b*10 + c
    float s = 0.f;
    for (int sl = q; sl < 160; sl += 4) s += partial[sl * 160 + o];
    red[q][o] = s;
    __syncthreads();
    if (tid < 160)
        out[tid] = red[0][tid] + red[1][tid] + red[2][tid] + red[3][tid]
                 + linB[tid % 10];
}

// ---------------------------------------------------------------------------
extern "C" void kernel_launch(void* const* d_in, const int* in_sizes, int n_in,
                              void* d_out, int out_size, void* d_ws, size_t ws_size,
                              hipStream_t stream) {
    const float* x     = (const float*)d_in[0];
    const float* Wk    = (const float*)d_in[1];
    const float* bias  = (const float*)d_in[2];
    const float* gamma = (const float*)d_in[3];
    const float* beta  = (const float*)d_in[4];
    const float* linW  = (const float*)d_in[5];
    const float* linB  = (const float*)d_in[6];
    float* out = (float*)d_out;

    float* feat    = (float*)d_ws;                 // 320000 f
    float* partial = feat + NBATCH * FEAT_DIM;     // 160*160 f

    rocket_gemm<<<dim3(8, 5, NBATCH), 256, 0, stream>>>(x, Wk, bias, feat);
    bn_gemv<<<dim3(160), 256, 0, stream>>>(feat, gamma, beta, linW, partial);
    gemv_final<<<dim3(1), 640, 0, stream>>>(partial, linB, out);
}